// Round 1
// baseline (331.186 us; speedup 1.0000x reference)
//
#include <hip/hip_runtime.h>
#include <hip/hip_bf16.h>
#include <cstdint>
#include <cstddef>

#define BATCH 32
#define CIN   256
#define COUT  256
#define HH    56
#define WW    56
#define HP    60      // padded rows: 0..57 used (h=-1..56), 58/59 slack (zero)
#define WPAD  64      // padded cols: 0..57 used (w=-1..56), rest zero
#define KTOT  2304    // 9 * 256

typedef __attribute__((ext_vector_type(4))) float f32x4;
typedef __attribute__((ext_vector_type(8))) short short8;

// ---------------- BFP quantize + NCHW->padded-NHWC bf16 repack ----------------
__global__ void quant_kernel(const float* __restrict__ x, unsigned short* __restrict__ xq)
{
    const int h   = blockIdx.x;       // 0..55
    const int b   = blockIdx.y;       // 0..31
    const int tid = threadIdx.x;
    const int wv  = tid >> 6;
    const int w   = tid & 63;
    if (w >= WW) return;
    for (int cb = wv; cb < 8; cb += 4) {
        float v[32];
        float mx = 0.f;
        const float* xp = x + (((size_t)b * CIN + cb * 32) * HH + h) * WW + w;
#pragma unroll
        for (int c = 0; c < 32; ++c) {
            float t = xp[(size_t)c * HH * WW];
            v[c] = t;
            mx = fmaxf(mx, fabsf(t));
        }
        float m = fmaxf(mx, 1e-12f);
        int e;
        frexpf(m, &e);
        e -= 1;                                  // exact floor(log2(m))
        e = (e < -64) ? -64 : ((e > 63) ? 63 : e);
        float step = exp2f((float)(e - 7));
        float inv  = exp2f((float)(7 - e));
        unsigned short qb[32];
#pragma unroll
        for (int c = 0; c < 32; ++c) {
            float q = rintf(v[c] * inv);          // round-half-even, matches jnp.round
            q = fminf(fmaxf(q, -128.f), 127.f);
            float val = q * step;                 // exactly representable in bf16
            __hip_bfloat16 bv = __float2bfloat16(val);
            qb[c] = *reinterpret_cast<unsigned short*>(&bv);
        }
        unsigned short* dst = xq + (((size_t)b * HP + (h + 1)) * WPAD + (w + 1)) * CIN + cb * 32;
#pragma unroll
        for (int i = 0; i < 4; ++i)
            *reinterpret_cast<short8*>(dst + i * 8) = *reinterpret_cast<const short8*>(qb + i * 8);
    }
}

// ---------------- weight repack: OIHW fp32 -> [n][j=kh*3+kw][c] bf16 ----------------
__global__ void wrepack_kernel(const float* __restrict__ Wsrc, unsigned short* __restrict__ Wr)
{
    int idx = blockIdx.x * 256 + threadIdx.x;
    if (idx >= COUT * KTOT) return;
    int n = idx / KTOT;
    int r = idx % KTOT;
    int j = r >> 8;    // 0..8
    int c = r & 255;
    float val = Wsrc[((size_t)n * CIN + c) * 9 + j];
    __hip_bfloat16 bv = __float2bfloat16(val);
    Wr[idx] = *reinterpret_cast<unsigned short*>(&bv);
}

// ---------------- implicit-GEMM conv, 128x128 tile, bf16 MFMA ----------------
__device__ inline void gload_lds16(const void* g, void* l)
{
    __builtin_amdgcn_global_load_lds((const __attribute__((address_space(1))) void*)g,
                                     (__attribute__((address_space(3))) void*)l, 16, 0, 0);
}

__global__ __launch_bounds__(256) void conv_gemm_kernel(const unsigned short* __restrict__ xq,
                                                        const unsigned short* __restrict__ Wr,
                                                        float* __restrict__ out)
{
    __shared__ __align__(16) unsigned short As[128 * 64];
    __shared__ __align__(16) unsigned short Bs[128 * 64];
    const int mt  = blockIdx.x;   // 0..27
    const int nt  = blockIdx.y;   // 0..1
    const int b   = blockIdx.z;   // 0..31
    const int tid = threadIdx.x;
    const int wv  = tid >> 6;
    const int l   = tid & 63;
    const int ln  = l & 15;
    const int kg  = l >> 4;
    const int m0  = mt * 128;
    const int n0  = nt * 128;
    const int wm0 = (wv >> 1) * 64;
    const int wn0 = (wv & 1) * 64;

    const unsigned short* Ab = xq + (size_t)b * (HP * WPAD * CIN);

    f32x4 acc[4][4];
#pragma unroll
    for (int i = 0; i < 4; ++i)
#pragma unroll
        for (int jn = 0; jn < 4; ++jn) acc[i][jn] = (f32x4){0.f, 0.f, 0.f, 0.f};

    const int srow = l >> 3;   // row within wave's 8-row stripe
    const int scol = l & 7;    // 16B chunk within 128B row

    for (int t = 0; t < 36; ++t) {
        const int j    = t >> 2;
        const int cb   = t & 3;
        const int kh   = j / 3, kw = j % 3;
        const int aoff = (kh * WPAD + kw) * CIN + cb * 64;
        const int boff = j * 256 + cb * 64;
#pragma unroll
        for (int s = 0; s < 4; ++s) {
            const int row = s * 32 + wv * 8 + srow;
            gload_lds16(Ab + (size_t)(m0 + row) * CIN + aoff + scol * 8,
                        (void*)(As + row * 64 + scol * 8));
            gload_lds16(Wr + (size_t)(n0 + row) * KTOT + boff + scol * 8,
                        (void*)(Bs + row * 64 + scol * 8));
        }
        __syncthreads();
#pragma unroll
        for (int ks = 0; ks < 2; ++ks) {
            short8 af[4], bfr[4];
#pragma unroll
            for (int i = 0; i < 4; ++i)
                af[i] = *reinterpret_cast<const short8*>(&As[(wm0 + i * 16 + ln) * 64 + ks * 32 + kg * 8]);
#pragma unroll
            for (int i = 0; i < 4; ++i)
                bfr[i] = *reinterpret_cast<const short8*>(&Bs[(wn0 + i * 16 + ln) * 64 + ks * 32 + kg * 8]);
#pragma unroll
            for (int i = 0; i < 4; ++i)
#pragma unroll
                for (int jn = 0; jn < 4; ++jn)
                    acc[i][jn] = __builtin_amdgcn_mfma_f32_16x16x32_bf16(af[i], bfr[jn], acc[i][jn], 0, 0, 0);
        }
        __syncthreads();
    }

    // epilogue: C/D layout col=lane&15 (n), row=(lane>>4)*4+reg (m)
#pragma unroll
    for (int i = 0; i < 4; ++i) {
#pragma unroll
        for (int jn = 0; jn < 4; ++jn) {
            const int n     = n0 + wn0 + jn * 16 + ln;
            const int mbase = m0 + wm0 + i * 16 + kg * 4;
#pragma unroll
            for (int r = 0; r < 4; ++r) {
                const int mm = mbase + r;
                const int h = mm >> 6, w = mm & 63;
                if (w < WW)
                    out[(((size_t)b * COUT + n) * HH + h) * WW + w] = acc[i][jn][r];
            }
        }
    }
}

// ---------------- BatchNorm stats (training-mode, biased var) ----------------
__global__ void bn_stats_kernel(const float* __restrict__ y, float* __restrict__ sums)
{
    const int o = blockIdx.x, b = blockIdx.y;
    const float* p = y + ((size_t)b * COUT + o) * (HH * WW);
    float s = 0.f, s2 = 0.f;
    for (int i = threadIdx.x; i < HH * WW; i += 256) {
        float v = p[i];
        s += v;
        s2 += v * v;
    }
#pragma unroll
    for (int off = 32; off > 0; off >>= 1) {
        s  += __shfl_down(s, off);
        s2 += __shfl_down(s2, off);
    }
    __shared__ float ls[4], ls2[4];
    const int wv = threadIdx.x >> 6, lane = threadIdx.x & 63;
    if (lane == 0) { ls[wv] = s; ls2[wv] = s2; }
    __syncthreads();
    if (threadIdx.x == 0) {
        atomicAdd(&sums[o],        ls[0] + ls[1] + ls[2] + ls[3]);
        atomicAdd(&sums[COUT + o], ls2[0] + ls2[1] + ls2[2] + ls2[3]);
    }
}

// ---------------- BN normalize + affine + ReLU (in place) ----------------
__global__ void bn_apply_kernel(float* __restrict__ y, const float* __restrict__ sums,
                                const float* __restrict__ gamma, const float* __restrict__ beta)
{
    const int o = blockIdx.x, b = blockIdx.y;
    const float N = (float)(BATCH * HH * WW);
    const float mean = sums[o] / N;
    const float var  = sums[COUT + o] / N - mean * mean;
    const float inv  = 1.f / sqrtf(var + 1e-5f);
    const float a  = gamma[o] * inv;
    const float bb = beta[o] - mean * a;
    float* p = y + ((size_t)b * COUT + o) * (HH * WW);
    for (int i = threadIdx.x; i < HH * WW; i += 256)
        p[i] = fmaxf(p[i] * a + bb, 0.f);
}

extern "C" void kernel_launch(void* const* d_in, const int* in_sizes, int n_in,
                              void* d_out, int out_size, void* d_ws, size_t ws_size,
                              hipStream_t stream)
{
    const float* x     = (const float*)d_in[0];
    const float* Wsrc  = (const float*)d_in[1];
    const float* gamma = (const float*)d_in[2];
    const float* beta  = (const float*)d_in[3];
    float* out = (float*)d_out;

    char* ws = (char*)d_ws;
    const size_t XQ_BYTES = (size_t)BATCH * HP * WPAD * CIN * 2;  // 62,914,560
    const size_t WR_BYTES = (size_t)COUT * KTOT * 2;              //  1,179,648
    unsigned short* xq = (unsigned short*)ws;
    unsigned short* wr = (unsigned short*)(ws + XQ_BYTES);
    float* sums = (float*)(ws + XQ_BYTES + WR_BYTES);

    hipMemsetAsync(xq, 0, XQ_BYTES, stream);                  // zero padding (and interior; rewritten)
    hipMemsetAsync(sums, 0, 2 * COUT * sizeof(float), stream);

    quant_kernel<<<dim3(HH, BATCH), 256, 0, stream>>>(x, xq);
    wrepack_kernel<<<(COUT * KTOT + 255) / 256, 256, 0, stream>>>(Wsrc, wr);
    conv_gemm_kernel<<<dim3(28, 2, BATCH), 256, 0, stream>>>(xq, wr, out);
    bn_stats_kernel<<<dim3(COUT, BATCH), 256, 0, stream>>>(out, sums);
    bn_apply_kernel<<<dim3(COUT, BATCH), 256, 0, stream>>>(out, sums, gamma, beta);
}

// Round 2
// 259.303 us; speedup vs baseline: 1.2772x; 1.2772x over previous
//
#include <hip/hip_runtime.h>
#include <hip/hip_bf16.h>
#include <cstdint>
#include <cstddef>

#define BATCH 32
#define CIN   256
#define COUT  256
#define HH    56
#define WW    56
#define HP    60      // padded rows: 0..57 read; 58/59 slack (zeroed)
#define WPAD  64      // padded cols: 0,57 are conv zero-pad; 58..63 slack (zeroed)
#define KTOT  2304    // 9 * 256
#define NT    72      // K-tiles of 32

typedef __attribute__((ext_vector_type(4))) float f32x4;
typedef __attribute__((ext_vector_type(8))) short short8;

// ---------------- zero only the padding cells of xq (12.4 MB, not 63 MB) ----------------
__global__ void zeropad_kernel(unsigned short* __restrict__ xq)
{
    const int b   = blockIdx.y;
    const int idx = blockIdx.x * 256 + threadIdx.x;   // 0..22527
    const int pos = idx >> 5;
    const int ch  = (idx & 31) * 8;
    int hp, wp;
    if (pos < 256) {                     // rows {0,57,58,59} full
        int r = pos >> 6;
        hp = (r == 0) ? 0 : 56 + r;
        wp = pos & 63;
    } else {                             // rows 1..56, cols {0,57..63}
        int i2 = pos - 256;
        int c  = i2 & 7;
        hp = (i2 >> 3) + 1;
        wp = (c == 0) ? 0 : 56 + c;
    }
    short8 z = {0, 0, 0, 0, 0, 0, 0, 0};
    *reinterpret_cast<short8*>(xq + (((size_t)b * HP + hp) * WPAD + wp) * CIN + ch) = z;
}

// ---------------- BFP quantize + NCHW->padded-NHWC bf16 repack ----------------
__global__ void quant_kernel(const float* __restrict__ x, unsigned short* __restrict__ xq)
{
    const int h   = blockIdx.x;       // 0..55
    const int b   = blockIdx.y;       // 0..31
    const int tid = threadIdx.x;
    const int wv  = tid >> 6;
    const int w   = tid & 63;
    if (w >= WW) return;
    for (int cb = wv; cb < 8; cb += 4) {
        float v[32];
        float mx = 0.f;
        const float* xp = x + (((size_t)b * CIN + cb * 32) * HH + h) * WW + w;
#pragma unroll
        for (int c = 0; c < 32; ++c) {
            float t = xp[(size_t)c * HH * WW];
            v[c] = t;
            mx = fmaxf(mx, fabsf(t));
        }
        float m = fmaxf(mx, 1e-12f);
        int e;
        frexpf(m, &e);
        e -= 1;                                  // exact floor(log2(m))
        e = (e < -64) ? -64 : ((e > 63) ? 63 : e);
        float step = exp2f((float)(e - 7));
        float inv  = exp2f((float)(7 - e));
        unsigned short qb[32];
#pragma unroll
        for (int c = 0; c < 32; ++c) {
            float q = rintf(v[c] * inv);          // round-half-even, matches jnp.round
            q = fminf(fmaxf(q, -128.f), 127.f);
            float val = q * step;                 // exactly representable in bf16
            __hip_bfloat16 bv = __float2bfloat16(val);
            qb[c] = *reinterpret_cast<unsigned short*>(&bv);
        }
        unsigned short* dst = xq + (((size_t)b * HP + (h + 1)) * WPAD + (w + 1)) * CIN + cb * 32;
#pragma unroll
        for (int i = 0; i < 4; ++i)
            *reinterpret_cast<short8*>(dst + i * 8) = *reinterpret_cast<const short8*>(qb + i * 8);
    }
}

// ---------------- weight repack: OIHW fp32 -> [n][j=kh*3+kw][c] bf16 ----------------
__global__ void wrepack_kernel(const float* __restrict__ Wsrc, unsigned short* __restrict__ Wr)
{
    int idx = blockIdx.x * 256 + threadIdx.x;
    if (idx >= COUT * KTOT) return;
    int n = idx / KTOT;
    int r = idx % KTOT;
    int j = r >> 8;    // 0..8
    int c = r & 255;
    float val = Wsrc[((size_t)n * CIN + c) * 9 + j];
    __hip_bfloat16 bv = __float2bfloat16(val);
    Wr[idx] = *reinterpret_cast<unsigned short*>(&bv);
}

// ---------------- implicit-GEMM conv, 256x256 tile, BK=32, 4-buf pipelined ----------------
__device__ __forceinline__ void gload_lds16(const void* g, void* l)
{
    __builtin_amdgcn_global_load_lds((const __attribute__((address_space(1))) void*)g,
                                     (__attribute__((address_space(3))) void*)l, 16, 0, 0);
}

#define SCB() __builtin_amdgcn_sched_barrier(0)
#define BAR() do { SCB(); __builtin_amdgcn_s_barrier(); SCB(); } while (0)
#define VMWAIT(n) do { asm volatile("s_waitcnt vmcnt(" #n ")" ::: "memory"); } while (0)

#define MFMA4(av, r)                                                                     \
    acc[r][0] = __builtin_amdgcn_mfma_f32_16x16x32_bf16(av, bfr0, acc[r][0], 0, 0, 0);   \
    acc[r][1] = __builtin_amdgcn_mfma_f32_16x16x32_bf16(av, bfr1, acc[r][1], 0, 0, 0);   \
    acc[r][2] = __builtin_amdgcn_mfma_f32_16x16x32_bf16(av, bfr2, acc[r][2], 0, 0, 0);   \
    acc[r][3] = __builtin_amdgcn_mfma_f32_16x16x32_bf16(av, bfr3, acc[r][3], 0, 0, 0);

// One K-tile = 4 phases. Phase p: ds-read A-frags 2p,2p+1 (+B frags in ph0),
// issue 1 half-tile global_load_lds for tile t+3, barrier, 8 MFMA, barrier.
// vmcnt(8) once per tile (2 tiles = 8 loads in flight) -- never drained to 0.
#define K_ITER(T, STG, VMTAIL) do {                                                      \
    const int t_ = (T);                                                                  \
    const unsigned short* Ac = As + (t_ & 3) * 8192;                                     \
    const unsigned short* Bc = Bs + (t_ & 3) * 8192;                                     \
    short8 bfr0, bfr1, bfr2, bfr3, a0, a1;                                               \
    /* ---- phase 0 ---- */                                                              \
    a0   = *(const short8*)(Ac + ardk + 0 * 512);                                        \
    a1   = *(const short8*)(Ac + ardk + 1 * 512);                                        \
    bfr0 = *(const short8*)(Bc + brdk + 0 * 512);                                        \
    bfr1 = *(const short8*)(Bc + brdk + 1 * 512);                                        \
    bfr2 = *(const short8*)(Bc + brdk + 2 * 512);                                        \
    bfr3 = *(const short8*)(Bc + brdk + 3 * 512);                                        \
    if (STG) stageA(t_ + 3, 0);                                                          \
    BAR();                                                                               \
    __builtin_amdgcn_s_setprio(1);                                                       \
    MFMA4(a0, 0) MFMA4(a1, 1)                                                            \
    __builtin_amdgcn_s_setprio(0);                                                       \
    BAR();                                                                               \
    /* ---- phase 1 ---- */                                                              \
    a0 = *(const short8*)(Ac + ardk + 2 * 512);                                          \
    a1 = *(const short8*)(Ac + ardk + 3 * 512);                                          \
    if (STG) stageA(t_ + 3, 1);                                                          \
    BAR();                                                                               \
    __builtin_amdgcn_s_setprio(1);                                                       \
    MFMA4(a0, 2) MFMA4(a1, 3)                                                            \
    __builtin_amdgcn_s_setprio(0);                                                       \
    BAR();                                                                               \
    /* ---- phase 2 ---- */                                                              \
    a0 = *(const short8*)(Ac + ardk + 4 * 512);                                          \
    a1 = *(const short8*)(Ac + ardk + 5 * 512);                                          \
    if (STG) stageB(t_ + 3, 0);                                                          \
    BAR();                                                                               \
    __builtin_amdgcn_s_setprio(1);                                                       \
    MFMA4(a0, 4) MFMA4(a1, 5)                                                            \
    __builtin_amdgcn_s_setprio(0);                                                       \
    BAR();                                                                               \
    /* ---- phase 3 ---- */                                                              \
    a0 = *(const short8*)(Ac + ardk + 6 * 512);                                          \
    a1 = *(const short8*)(Ac + ardk + 7 * 512);                                          \
    if (STG) stageB(t_ + 3, 1);                                                          \
    BAR();                                                                               \
    __builtin_amdgcn_s_setprio(1);                                                       \
    MFMA4(a0, 6) MFMA4(a1, 7)                                                            \
    __builtin_amdgcn_s_setprio(0);                                                       \
    VMTAIL;                                                                              \
    BAR();                                                                               \
} while (0)

__global__ __launch_bounds__(512, 2) void conv_gemm_kernel(const unsigned short* __restrict__ xq,
                                                           const unsigned short* __restrict__ Wr,
                                                           float* __restrict__ out)
{
    extern __shared__ __align__(16) unsigned short lds[];
    unsigned short* As = lds;              // 4 bufs x 256 rows x 32 (64 KB)
    unsigned short* Bs = lds + 4 * 8192;   // 4 bufs x 256 rows x 32 (64 KB)

    const int bid  = blockIdx.x;                    // 0..447
    const int blk  = (bid & 7) * 56 + (bid >> 3);   // bijective XCD swizzle (448 = 8*56)
    const int b    = blk / 14;
    const int m0   = (blk % 14) * 256;
    const int tid  = threadIdx.x;
    const int wv   = tid >> 6;          // 0..7
    const int lane = tid & 63;
    const int ln   = lane & 15;
    const int kg   = lane >> 4;         // k-group 0..3
    const int wm   = wv >> 2;           // 0..1
    const int wn   = wv & 3;            // 0..3

    const unsigned short* Ab = xq + (size_t)b * (HP * WPAD * CIN);

    // per-lane constant LDS read offsets (elements); + frag*512
    const int ardk = (wm * 128 + ln) * 32 + kg * 8;
    const int brdk = (wn * 64 + ln) * 32 + kg * 8;
    // staging per-lane offsets
    const int sR = lane >> 2;           // row within 16-row group
    const int sC = (lane & 3) * 8;      // elem chunk

    auto stageA = [&](int tt, int q) {
        int j = tt >> 3, cb = tt & 7;
        int kh = j / 3, kw = j - 3 * kh;
        int aoff = (kh * WPAD + kw) * CIN + cb * 32;
        int g = 2 * wv + q;
        gload_lds16(Ab + (size_t)(m0 + g * 16 + sR) * CIN + aoff + sC,
                    (void*)(As + (tt & 3) * 8192 + g * 512));
    };
    auto stageB = [&](int tt, int q) {
        int j = tt >> 3, cb = tt & 7;
        int g = 2 * wv + q;
        gload_lds16(Wr + (size_t)(g * 16 + sR) * KTOT + j * 256 + cb * 32 + sC,
                    (void*)(Bs + (tt & 3) * 8192 + g * 512));
    };

    f32x4 acc[8][4];
#pragma unroll
    for (int i = 0; i < 8; ++i)
#pragma unroll
        for (int jn = 0; jn < 4; ++jn) acc[i][jn] = (f32x4){0.f, 0.f, 0.f, 0.f};

    // prologue: stage tiles 0,1,2 (12 loads/thread); wait for tile 0 only
    stageA(0, 0); stageA(0, 1); stageB(0, 0); stageB(0, 1);
    stageA(1, 0); stageA(1, 1); stageB(1, 0); stageB(1, 1);
    stageA(2, 0); stageA(2, 1); stageB(2, 0); stageB(2, 1);
    VMWAIT(8);
    BAR();

    for (int t = 0; t < NT - 3; ++t) { K_ITER(t, true, VMWAIT(8)); }
    K_ITER(NT - 3, false, VMWAIT(4));
    K_ITER(NT - 2, false, VMWAIT(0));
    K_ITER(NT - 1, false, (void)0);

    // epilogue: C/D layout col=lane&15 (n), row=(lane>>4)*4+reg (m)
#pragma unroll
    for (int i = 0; i < 8; ++i) {
#pragma unroll
        for (int jn = 0; jn < 4; ++jn) {
            const int n  = wn * 64 + jn * 16 + ln;
            const int mb = m0 + wm * 128 + i * 16 + kg * 4;
#pragma unroll
            for (int r = 0; r < 4; ++r) {
                const int mm = mb + r;
                const int h = mm >> 6, w = mm & 63;
                if (w < WW)
                    out[(((size_t)b * COUT + n) * HH + h) * WW + w] = acc[i][jn][r];
            }
        }
    }
}

// ---------------- BatchNorm stats (training-mode, biased var) ----------------
__global__ void bn_stats_kernel(const float* __restrict__ y, float* __restrict__ sums)
{
    const int o = blockIdx.x, b = blockIdx.y;
    const float* p = y + ((size_t)b * COUT + o) * (HH * WW);
    float s = 0.f, s2 = 0.f;
    for (int i = threadIdx.x; i < HH * WW; i += 256) {
        float v = p[i];
        s += v;
        s2 += v * v;
    }
#pragma unroll
    for (int off = 32; off > 0; off >>= 1) {
        s  += __shfl_down(s, off);
        s2 += __shfl_down(s2, off);
    }
    __shared__ float ls[4], ls2[4];
    const int wv = threadIdx.x >> 6, lane = threadIdx.x & 63;
    if (lane == 0) { ls[wv] = s; ls2[wv] = s2; }
    __syncthreads();
    if (threadIdx.x == 0) {
        atomicAdd(&sums[o],        ls[0] + ls[1] + ls[2] + ls[3]);
        atomicAdd(&sums[COUT + o], ls2[0] + ls2[1] + ls2[2] + ls2[3]);
    }
}

// ---------------- BN normalize + affine + ReLU (in place) ----------------
__global__ void bn_apply_kernel(float* __restrict__ y, const float* __restrict__ sums,
                                const float* __restrict__ gamma, const float* __restrict__ beta)
{
    const int o = blockIdx.x, b = blockIdx.y;
    const float N = (float)(BATCH * HH * WW);
    const float mean = sums[o] / N;
    const float var  = sums[COUT + o] / N - mean * mean;
    const float inv  = 1.f / sqrtf(var + 1e-5f);
    const float a  = gamma[o] * inv;
    const float bb = beta[o] - mean * a;
    float* p = y + ((size_t)b * COUT + o) * (HH * WW);
    for (int i = threadIdx.x; i < HH * WW; i += 256)
        p[i] = fmaxf(p[i] * a + bb, 0.f);
}

extern "C" void kernel_launch(void* const* d_in, const int* in_sizes, int n_in,
                              void* d_out, int out_size, void* d_ws, size_t ws_size,
                              hipStream_t stream)
{
    const float* x     = (const float*)d_in[0];
    const float* Wsrc  = (const float*)d_in[1];
    const float* gamma = (const float*)d_in[2];
    const float* beta  = (const float*)d_in[3];
    float* out = (float*)d_out;

    char* ws = (char*)d_ws;
    const size_t XQ_BYTES = (size_t)BATCH * HP * WPAD * CIN * 2;  // 62,914,560
    const size_t WR_BYTES = (size_t)COUT * KTOT * 2;              //  1,179,648
    unsigned short* xq = (unsigned short*)ws;
    unsigned short* wr = (unsigned short*)(ws + XQ_BYTES);
    float* sums = (float*)(ws + XQ_BYTES + WR_BYTES);

    hipMemsetAsync(sums, 0, 2 * COUT * sizeof(float), stream);

    zeropad_kernel<<<dim3(88, BATCH), 256, 0, stream>>>(xq);
    quant_kernel<<<dim3(HH, BATCH), 256, 0, stream>>>(x, xq);
    wrepack_kernel<<<(COUT * KTOT + 255) / 256, 256, 0, stream>>>(Wsrc, wr);

    hipFuncSetAttribute(reinterpret_cast<const void*>(&conv_gemm_kernel),
                        hipFuncAttributeMaxDynamicSharedMemorySize, 131072);
    conv_gemm_kernel<<<448, 512, 131072, stream>>>(xq, wr, out);

    bn_stats_kernel<<<dim3(COUT, BATCH), 256, 0, stream>>>(out, sums);
    bn_apply_kernel<<<dim3(COUT, BATCH), 256, 0, stream>>>(out, sums, gamma, beta);
}

// Round 3
// 242.840 us; speedup vs baseline: 1.3638x; 1.0678x over previous
//
#include <hip/hip_runtime.h>
#include <hip/hip_bf16.h>
#include <cstdint>
#include <cstddef>

#define BATCH 32
#define CIN   256
#define COUT  256
#define HH    56
#define WW    56
#define HP    60      // padded rows: 0..57 read; 58/59 slack (zeroed)
#define WPAD  64      // padded cols: 0,57 are conv zero-pad; 58..63 slack (zeroed)
#define KTOT  2304    // 9 * 256
#define NT    72      // K-tiles of 32

typedef __attribute__((ext_vector_type(4))) float f32x4;
typedef __attribute__((ext_vector_type(8))) short short8;

// ---------------- zero only the padding cells of xq (12.4 MB, not 63 MB) ----------------
__global__ void zeropad_kernel(unsigned short* __restrict__ xq)
{
    const int b   = blockIdx.y;
    const int idx = blockIdx.x * 256 + threadIdx.x;   // 0..22527
    const int pos = idx >> 5;
    const int ch  = (idx & 31) * 8;
    int hp, wp;
    if (pos < 256) {                     // rows {0,57,58,59} full
        int r = pos >> 6;
        hp = (r == 0) ? 0 : 56 + r;
        wp = pos & 63;
    } else {                             // rows 1..56, cols {0,57..63}
        int i2 = pos - 256;
        int c  = i2 & 7;
        hp = (i2 >> 3) + 1;
        wp = (c == 0) ? 0 : 56 + c;
    }
    short8 z = {0, 0, 0, 0, 0, 0, 0, 0};
    *reinterpret_cast<short8*>(xq + (((size_t)b * HP + hp) * WPAD + wp) * CIN + ch) = z;
}

// ---------------- BFP quantize + NCHW->padded-NHWC bf16 repack ----------------
__global__ void quant_kernel(const float* __restrict__ x, unsigned short* __restrict__ xq)
{
    const int h   = blockIdx.x;       // 0..55
    const int b   = blockIdx.y;       // 0..31
    const int tid = threadIdx.x;
    const int wv  = tid >> 6;
    const int w   = tid & 63;
    if (w >= WW) return;
    for (int cb = wv; cb < 8; cb += 4) {
        float v[32];
        float mx = 0.f;
        const float* xp = x + (((size_t)b * CIN + cb * 32) * HH + h) * WW + w;
#pragma unroll
        for (int c = 0; c < 32; ++c) {
            float t = xp[(size_t)c * HH * WW];
            v[c] = t;
            mx = fmaxf(mx, fabsf(t));
        }
        float m = fmaxf(mx, 1e-12f);
        int e;
        frexpf(m, &e);
        e -= 1;                                  // exact floor(log2(m))
        e = (e < -64) ? -64 : ((e > 63) ? 63 : e);
        float step = exp2f((float)(e - 7));
        float inv  = exp2f((float)(7 - e));
        unsigned short qb[32];
#pragma unroll
        for (int c = 0; c < 32; ++c) {
            float q = rintf(v[c] * inv);          // round-half-even, matches jnp.round
            q = fminf(fmaxf(q, -128.f), 127.f);
            float val = q * step;                 // exactly representable in bf16
            __hip_bfloat16 bv = __float2bfloat16(val);
            qb[c] = *reinterpret_cast<unsigned short*>(&bv);
        }
        unsigned short* dst = xq + (((size_t)b * HP + (h + 1)) * WPAD + (w + 1)) * CIN + cb * 32;
#pragma unroll
        for (int i = 0; i < 4; ++i)
            *reinterpret_cast<short8*>(dst + i * 8) = *reinterpret_cast<const short8*>(qb + i * 8);
    }
}

// ---------------- weight repack: OIHW fp32 -> [n][j=kh*3+kw][c] bf16 ----------------
__global__ void wrepack_kernel(const float* __restrict__ Wsrc, unsigned short* __restrict__ Wr)
{
    int idx = blockIdx.x * 256 + threadIdx.x;
    if (idx >= COUT * KTOT) return;
    int n = idx / KTOT;
    int r = idx % KTOT;
    int j = r >> 8;    // 0..8
    int c = r & 255;
    float val = Wsrc[((size_t)n * CIN + c) * 9 + j];
    __hip_bfloat16 bv = __float2bfloat16(val);
    Wr[idx] = *reinterpret_cast<unsigned short*>(&bv);
}

// ---------------- implicit-GEMM conv, 256x256 tile, BK=32, 4-buf pipelined ----------------
// LDS tile layout (fragment order): 16-row groups of 1024B; within a group,
// byte offset = kg*256 + row_in_group*16, so MFMA lane l (=kg*16+ln) reads at
// byte l*16 -> conflict-free ds_read_b128. global_load_lds writes linearly at
// lane*16, so the GLOBAL source address is pre-swizzled (row=l&15, chunk=l>>4).
__device__ __forceinline__ void gload_lds16(const void* g, void* l)
{
    __builtin_amdgcn_global_load_lds((const __attribute__((address_space(1))) void*)g,
                                     (__attribute__((address_space(3))) void*)l, 16, 0, 0);
}

#define SCB() __builtin_amdgcn_sched_barrier(0)
#define BAR() do { SCB(); __builtin_amdgcn_s_barrier(); SCB(); } while (0)
#define VMWAIT(n) do { asm volatile("s_waitcnt vmcnt(" #n ")" ::: "memory"); } while (0)

#define MFMA4(av, r)                                                                     \
    acc[r][0] = __builtin_amdgcn_mfma_f32_16x16x32_bf16(av, bfr0, acc[r][0], 0, 0, 0);   \
    acc[r][1] = __builtin_amdgcn_mfma_f32_16x16x32_bf16(av, bfr1, acc[r][1], 0, 0, 0);   \
    acc[r][2] = __builtin_amdgcn_mfma_f32_16x16x32_bf16(av, bfr2, acc[r][2], 0, 0, 0);   \
    acc[r][3] = __builtin_amdgcn_mfma_f32_16x16x32_bf16(av, bfr3, acc[r][3], 0, 0, 0);

// One K-tile = 4 phases. Phase p: ds-read A-frags 2p,2p+1 (+B frags in ph0),
// issue 1 half-tile global_load_lds for tile t+3, barrier, 8 MFMA, barrier.
// vmcnt(8) once per tile (2 tiles = 8 loads in flight) -- never drained to 0.
#define K_ITER(T, STG, VMTAIL) do {                                                      \
    const int t_ = (T);                                                                  \
    const unsigned short* Ac = As + (t_ & 3) * 8192;                                     \
    const unsigned short* Bc = Bs + (t_ & 3) * 8192;                                     \
    short8 bfr0, bfr1, bfr2, bfr3, a0, a1;                                               \
    /* ---- phase 0 ---- */                                                              \
    a0   = *(const short8*)(Ac + ardk + 0 * 512);                                        \
    a1   = *(const short8*)(Ac + ardk + 1 * 512);                                        \
    bfr0 = *(const short8*)(Bc + brdk + 0 * 512);                                        \
    bfr1 = *(const short8*)(Bc + brdk + 1 * 512);                                        \
    bfr2 = *(const short8*)(Bc + brdk + 2 * 512);                                        \
    bfr3 = *(const short8*)(Bc + brdk + 3 * 512);                                        \
    if (STG) stageA(t_ + 3, 0);                                                          \
    BAR();                                                                               \
    __builtin_amdgcn_s_setprio(1);                                                       \
    MFMA4(a0, 0) MFMA4(a1, 1)                                                            \
    __builtin_amdgcn_s_setprio(0);                                                       \
    BAR();                                                                               \
    /* ---- phase 1 ---- */                                                              \
    a0 = *(const short8*)(Ac + ardk + 2 * 512);                                          \
    a1 = *(const short8*)(Ac + ardk + 3 * 512);                                          \
    if (STG) stageA(t_ + 3, 1);                                                          \
    BAR();                                                                               \
    __builtin_amdgcn_s_setprio(1);                                                       \
    MFMA4(a0, 2) MFMA4(a1, 3)                                                            \
    __builtin_amdgcn_s_setprio(0);                                                       \
    BAR();                                                                               \
    /* ---- phase 2 ---- */                                                              \
    a0 = *(const short8*)(Ac + ardk + 4 * 512);                                          \
    a1 = *(const short8*)(Ac + ardk + 5 * 512);                                          \
    if (STG) stageB(t_ + 3, 0);                                                          \
    BAR();                                                                               \
    __builtin_amdgcn_s_setprio(1);                                                       \
    MFMA4(a0, 4) MFMA4(a1, 5)                                                            \
    __builtin_amdgcn_s_setprio(0);                                                       \
    BAR();                                                                               \
    /* ---- phase 3 ---- */                                                              \
    a0 = *(const short8*)(Ac + ardk + 6 * 512);                                          \
    a1 = *(const short8*)(Ac + ardk + 7 * 512);                                          \
    if (STG) stageB(t_ + 3, 1);                                                          \
    BAR();                                                                               \
    __builtin_amdgcn_s_setprio(1);                                                       \
    MFMA4(a0, 6) MFMA4(a1, 7)                                                            \
    __builtin_amdgcn_s_setprio(0);                                                       \
    VMTAIL;                                                                              \
    BAR();                                                                               \
} while (0)

__global__ __launch_bounds__(512, 2) void conv_gemm_kernel(const unsigned short* __restrict__ xq,
                                                           const unsigned short* __restrict__ Wr,
                                                           float* __restrict__ out,
                                                           float* __restrict__ sums)
{
    extern __shared__ __align__(16) unsigned short lds[];
    unsigned short* As = lds;              // 4 bufs x 16 groups x 512 elem (64 KB)
    unsigned short* Bs = lds + 4 * 8192;   // 4 bufs x 16 groups x 512 elem (64 KB)

    const int bid  = blockIdx.x;                    // 0..447
    const int blk  = (bid & 7) * 56 + (bid >> 3);   // bijective XCD swizzle (448 = 8*56)
    const int b    = blk / 14;
    const int m0   = (blk % 14) * 256;
    const int tid  = threadIdx.x;
    const int wv   = tid >> 6;          // 0..7
    const int lane = tid & 63;
    const int ln   = lane & 15;
    const int kg   = lane >> 4;         // k-group 0..3
    const int wm   = wv >> 2;           // 0..1
    const int wn   = wv & 3;            // 0..3

    const unsigned short* Ab = xq + (size_t)b * (HP * WPAD * CIN);

    // fragment-order LDS read offsets (elements); frag f at +f*512
    const int ardk = wm * 4096 + lane * 8;
    const int brdk = wn * 2048 + lane * 8;
    // pre-swizzled global source offsets for linear global_load_lds dest
    const int sR = lane & 15;           // row within 16-row group
    const int sC = (lane >> 4) * 8;     // 8-elem (16B) chunk within 64B row

    auto stageA = [&](int tt, int q) {
        int j = tt >> 3, cb = tt & 7;
        int kh = j / 3, kw = j - 3 * kh;
        int aoff = (kh * WPAD + kw) * CIN + cb * 32;
        int g = 2 * wv + q;
        gload_lds16(Ab + (size_t)(m0 + g * 16 + sR) * CIN + aoff + sC,
                    (void*)(As + (tt & 3) * 8192 + g * 512));
    };
    auto stageB = [&](int tt, int q) {
        int j = tt >> 3, cb = tt & 7;
        int g = 2 * wv + q;
        gload_lds16(Wr + (size_t)(g * 16 + sR) * KTOT + j * 256 + cb * 32 + sC,
                    (void*)(Bs + (tt & 3) * 8192 + g * 512));
    };

    f32x4 acc[8][4];
#pragma unroll
    for (int i = 0; i < 8; ++i)
#pragma unroll
        for (int jn = 0; jn < 4; ++jn) acc[i][jn] = (f32x4){0.f, 0.f, 0.f, 0.f};

    // prologue: stage tiles 0,1,2 (12 loads/thread); wait for tile 0 only
    stageA(0, 0); stageA(0, 1); stageB(0, 0); stageB(0, 1);
    stageA(1, 0); stageA(1, 1); stageB(1, 0); stageB(1, 1);
    stageA(2, 0); stageA(2, 1); stageB(2, 0); stageB(2, 1);
    VMWAIT(8);
    BAR();

    for (int t = 0; t < NT - 3; ++t) { K_ITER(t, true, VMWAIT(8)); }
    K_ITER(NT - 3, false, VMWAIT(4));
    K_ITER(NT - 2, false, VMWAIT(0));
    K_ITER(NT - 1, false, (void)0);

    // epilogue: C/D layout col=lane&15 (n), row=(lane>>4)*4+reg (m).
    // r=0..3 are consecutive w -> f32x4 stores; w<56 mask == !(i%4==3 && kg>=2).
    // Fused BN stats: per-thread (s,s2) per n, shfl-reduce over kg, atomicAdd.
#pragma unroll
    for (int jn = 0; jn < 4; ++jn) {
        const int n = wn * 64 + jn * 16 + ln;
        float s = 0.f, s2 = 0.f;
#pragma unroll
        for (int i = 0; i < 8; ++i) {
            if ((i & 3) == 3 && kg >= 2) continue;   // w = 56..63: padding lanes
            const int mm = m0 + wm * 128 + i * 16 + kg * 4;
            const int h = mm >> 6, w = mm & 63;
            f32x4 v = acc[i][jn];
            s  += v[0] + v[1] + v[2] + v[3];
            s2 += v[0] * v[0] + v[1] * v[1] + v[2] * v[2] + v[3] * v[3];
            *reinterpret_cast<f32x4*>(&out[(((size_t)b * COUT + n) * HH + h) * WW + w]) = v;
        }
        s  += __shfl_xor(s, 16);  s  += __shfl_xor(s, 32);
        s2 += __shfl_xor(s2, 16); s2 += __shfl_xor(s2, 32);
        if (kg == 0) {
            atomicAdd(&sums[n], s);
            atomicAdd(&sums[COUT + n], s2);
        }
    }
}

// ---------------- BN normalize + affine + ReLU (in place) ----------------
__global__ void bn_apply_kernel(float* __restrict__ y, const float* __restrict__ sums,
                                const float* __restrict__ gamma, const float* __restrict__ beta)
{
    const int o = blockIdx.x, b = blockIdx.y;
    const float N = (float)(BATCH * HH * WW);
    const float mean = sums[o] / N;
    const float var  = sums[COUT + o] / N - mean * mean;
    const float inv  = 1.f / sqrtf(var + 1e-5f);
    const float a  = gamma[o] * inv;
    const float bb = beta[o] - mean * a;
    float* p = y + ((size_t)b * COUT + o) * (HH * WW);
    for (int i = threadIdx.x; i < HH * WW; i += 256)
        p[i] = fmaxf(p[i] * a + bb, 0.f);
}

extern "C" void kernel_launch(void* const* d_in, const int* in_sizes, int n_in,
                              void* d_out, int out_size, void* d_ws, size_t ws_size,
                              hipStream_t stream)
{
    const float* x     = (const float*)d_in[0];
    const float* Wsrc  = (const float*)d_in[1];
    const float* gamma = (const float*)d_in[2];
    const float* beta  = (const float*)d_in[3];
    float* out = (float*)d_out;

    char* ws = (char*)d_ws;
    const size_t XQ_BYTES = (size_t)BATCH * HP * WPAD * CIN * 2;  // 62,914,560
    const size_t WR_BYTES = (size_t)COUT * KTOT * 2;              //  1,179,648
    unsigned short* xq = (unsigned short*)ws;
    unsigned short* wr = (unsigned short*)(ws + XQ_BYTES);
    float* sums = (float*)(ws + XQ_BYTES + WR_BYTES);

    hipMemsetAsync(sums, 0, 2 * COUT * sizeof(float), stream);

    zeropad_kernel<<<dim3(88, BATCH), 256, 0, stream>>>(xq);
    quant_kernel<<<dim3(HH, BATCH), 256, 0, stream>>>(x, xq);
    wrepack_kernel<<<(COUT * KTOT + 255) / 256, 256, 0, stream>>>(Wsrc, wr);

    hipFuncSetAttribute(reinterpret_cast<const void*>(&conv_gemm_kernel),
                        hipFuncAttributeMaxDynamicSharedMemorySize, 131072);
    conv_gemm_kernel<<<448, 512, 131072, stream>>>(xq, wr, out, sums);

    bn_apply_kernel<<<dim3(COUT, BATCH), 256, 0, stream>>>(out, sums, gamma, beta);
}